// Round 1
// baseline (505.969 us; speedup 1.0000x reference)
//
#include <hip/hip_runtime.h>

// GAT_gate: B=8, N=2048, D=128
// out = coeff*x + (1-coeff)*relu(att@h), att = colsoftmax(mask(hA h^T + h hA^T))*adj
// Softmax stats are per-COLUMN j of the aggregation sum; e-values are small
// (|e| < ~6) so we use exp(e)/s[j] without max-subtraction (clamp 60 for safety).

#define B_ 8
#define N_ 2048
#define D_ 128

typedef __attribute__((ext_vector_type(8))) short short8;
typedef __attribute__((ext_vector_type(4))) float f32x4;

static __device__ __forceinline__ unsigned short f2bf(float f) {
  union { float f; unsigned int u; } v; v.f = f;
  unsigned int r = v.u + 0x7fffu + ((v.u >> 16) & 1u);
  return (unsigned short)(r >> 16);
}

// ---- workspace layout (bytes) ----
#define HB_OFF   ((size_t)0)          // bf16 h        [B][N][D]   4 MB
#define HAB_OFF  ((size_t)4194304)    // bf16 hA       [B][N][D]   4 MB
#define HBT_OFF  ((size_t)8388608)    // bf16 h^T      [B][D][N]   4 MB
#define BITS_OFF ((size_t)12582912)   // adj bitmask   [B][N][N/32] 16.78 MB
#define S_OFF    ((size_t)29360128)   // f32 colsum s  [B][N]      64 KB
#define WT_OFF   ((size_t)29425664)   // f32 W^T       [D][D]      64 KB

// ---------- prep: W transpose (tiny) ----------
__global__ void k_wt(const float* __restrict__ W, float* __restrict__ Wt) {
  int t = threadIdx.x;
  for (int i = t; i < 128 * 128; i += 256) {
    int d = i >> 7, f = i & 127;
    Wt[f * 128 + d] = W[i];
  }
}

// ---------- prep: adj -> bitmask via ballot ----------
__global__ void k_bits(const float* __restrict__ adj,
                       unsigned long long* __restrict__ bits) {
  size_t i = (size_t)blockIdx.x * 256 + threadIdx.x;
  bool v = adj[i] > 0.0f;
  unsigned long long m = __ballot(v);
  if ((threadIdx.x & 63) == 0) bits[i >> 6] = m;
}

// ---------- prep: h = xW^T + b (fp32), hA = h@A ; store bf16 ----------
__global__ __launch_bounds__(256) void k1(const float* __restrict__ x,
                                          const float* __restrict__ Wt,
                                          const float* __restrict__ Wb,
                                          const float* __restrict__ A,
                                          unsigned short* __restrict__ hb,
                                          unsigned short* __restrict__ hab) {
  __shared__ float xs[8][128];
  __shared__ float hs[8][128];
  const int t = threadIdx.x;
  const size_t rowbase = (size_t)blockIdx.x * 8;
  {
    int row = t >> 5, part = t & 31;
    *(f32x4*)&xs[row][part * 4] = *(const f32x4*)(x + (rowbase + row) * D_ + part * 4);
  }
  __syncthreads();
  const int d = t & 127, r2 = t >> 7;
  float a0 = 0, a1 = 0, a2 = 0, a3 = 0;
  for (int f = 0; f < 128; f++) {
    float wv = Wt[f * 128 + d];
    a0 += xs[r2 * 4 + 0][f] * wv;
    a1 += xs[r2 * 4 + 1][f] * wv;
    a2 += xs[r2 * 4 + 2][f] * wv;
    a3 += xs[r2 * 4 + 3][f] * wv;
  }
  float wb = Wb[d];
  a0 += wb; a1 += wb; a2 += wb; a3 += wb;
  hs[r2 * 4 + 0][d] = a0; hs[r2 * 4 + 1][d] = a1;
  hs[r2 * 4 + 2][d] = a2; hs[r2 * 4 + 3][d] = a3;
  hb[(rowbase + r2 * 4 + 0) * D_ + d] = f2bf(a0);
  hb[(rowbase + r2 * 4 + 1) * D_ + d] = f2bf(a1);
  hb[(rowbase + r2 * 4 + 2) * D_ + d] = f2bf(a2);
  hb[(rowbase + r2 * 4 + 3) * D_ + d] = f2bf(a3);
  __syncthreads();
  float b0 = 0, b1 = 0, b2 = 0, b3 = 0;
  for (int f = 0; f < 128; f++) {
    float av = A[f * 128 + d];
    b0 += hs[r2 * 4 + 0][f] * av;
    b1 += hs[r2 * 4 + 1][f] * av;
    b2 += hs[r2 * 4 + 2][f] * av;
    b3 += hs[r2 * 4 + 3][f] * av;
  }
  hab[(rowbase + r2 * 4 + 0) * D_ + d] = f2bf(b0);
  hab[(rowbase + r2 * 4 + 1) * D_ + d] = f2bf(b1);
  hab[(rowbase + r2 * 4 + 2) * D_ + d] = f2bf(b2);
  hab[(rowbase + r2 * 4 + 3) * D_ + d] = f2bf(b3);
}

// ---------- prep: hbT[b][d][n] = hb[b][n][d] ----------
__global__ __launch_bounds__(256) void k1t(const unsigned short* __restrict__ hb,
                                           unsigned short* __restrict__ hbt) {
  __shared__ unsigned short tile[64][136];
  const int t = threadIdx.x;
  const int b = blockIdx.y;
  const int nbase = blockIdx.x * 64;
#pragma unroll
  for (int k = 0; k < 4; k++) {
    int s = t + 256 * k;                 // 1024 slots of 16B in
    int row = s >> 4, part = s & 15;
    *(short8*)&tile[row][part * 8] =
        *(const short8*)(hb + ((size_t)(b * N_ + nbase + row)) * D_ + part * 8);
  }
  __syncthreads();
#pragma unroll
  for (int k = 0; k < 4; k++) {
    int s = t + 256 * k;                 // 1024 slots of 16B out
    int dd = s >> 3, part = s & 7;
    unsigned short tmp[8];
#pragma unroll
    for (int j = 0; j < 8; j++) tmp[j] = tile[part * 8 + j][dd];
    *(short8*)(hbt + ((size_t)(b * D_ + dd)) * N_ + nbase + part * 8) = *(short8*)tmp;
  }
}

// ---------- stats: s[b,k] = sum_j adj[j,k]*exp(e_sym[j,k]) ----------
// grid (ktile=64, jchunk=4, b=8); block 256 = 4 waves, wave w -> (jhalf=w>>1, khalf=w&1)
__global__ __launch_bounds__(256) void k2(const unsigned short* __restrict__ hb,
                                          const unsigned short* __restrict__ hab,
                                          const unsigned int* __restrict__ bits,
                                          float* __restrict__ s_out) {
  __shared__ unsigned short hj[32 * 136];
  __shared__ unsigned short haj[32 * 136];
  __shared__ float spart[4][16];
  const int t = threadIdx.x, w = t >> 6, lane = t & 63;
  const int q = lane >> 4, l15 = lane & 15;
  const int b = blockIdx.z, ktile = blockIdx.x, jchunk = blockIdx.y;
  const int jhalf = w >> 1, khalf = w & 1;
  const size_t krow = (size_t)b * N_ + ktile * 32 + khalf * 16 + l15;
  short8 bhk[4], bhak[4];
#pragma unroll
  for (int c = 0; c < 4; c++) {
    bhk[c]  = *(const short8*)(hb  + krow * D_ + c * 32 + q * 8);
    bhak[c] = *(const short8*)(hab + krow * D_ + c * 32 + q * 8);
  }
  float acc = 0.f;
  for (int jt = 0; jt < 16; jt++) {
    const int jbase = jchunk * 512 + jt * 32;
    __syncthreads();
#pragma unroll
    for (int k = 0; k < 2; k++) {
      int s = t + 256 * k;
      int row = s >> 4, part = s & 15;
      size_t g = ((size_t)b * N_ + jbase + row) * D_ + part * 8;
      *(short8*)(hj  + row * 136 + part * 8) = *(const short8*)(hb + g);
      *(short8*)(haj + row * 136 + part * 8) = *(const short8*)(hab + g);
    }
    __syncthreads();
    f32x4 e = (f32x4){0.f, 0.f, 0.f, 0.f};
    const int arow = jhalf * 16 + l15;
#pragma unroll
    for (int c = 0; c < 4; c++) {
      short8 a1 = *(const short8*)(haj + arow * 136 + c * 32 + q * 8);
      short8 a2 = *(const short8*)(hj  + arow * 136 + c * 32 + q * 8);
      e = __builtin_amdgcn_mfma_f32_16x16x32_bf16(a1, bhk[c],  e, 0, 0, 0);
      e = __builtin_amdgcn_mfma_f32_16x16x32_bf16(a2, bhak[c], e, 0, 0, 0);
    }
#pragma unroll
    for (int r = 0; r < 4; r++) {
      int jrow = jbase + jhalf * 16 + q * 4 + r;
      unsigned int mb = bits[((size_t)b * N_ + jrow) * (N_ / 32) + ktile];
      if ((mb >> (khalf * 16 + l15)) & 1u) acc += __expf(fminf(e[r], 60.f));
    }
  }
  acc += __shfl_xor(acc, 16, 64);
  acc += __shfl_xor(acc, 32, 64);
  if (lane < 16) spart[w][lane] = acc;
  __syncthreads();
  if (t < 32) {
    float tot = spart[(t >> 4)][t & 15] + spart[(t >> 4) + 2][t & 15];
    atomicAdd(&s_out[(size_t)b * N_ + ktile * 32 + t], tot);
  }
}

// ---------- fused aggregate + gate: h' = relu(P@H), out = c*x+(1-c)*h' ----------
// grid (itile=64, 1, b=8); block 256 = 4 waves
// E phase: wave w -> quadrant (ihalf=w>>1, jhalf=w&1); PV: (ihalf=w>>1, dgroup=w&1)
__global__ __launch_bounds__(256) void k3(const unsigned short* __restrict__ hb,
                                          const unsigned short* __restrict__ hab,
                                          const unsigned short* __restrict__ hbt,
                                          const unsigned int* __restrict__ bits,
                                          const float* __restrict__ s_in,
                                          const float* __restrict__ x,
                                          const float* __restrict__ gw,
                                          const float* __restrict__ gb,
                                          float* __restrict__ out) {
  __shared__ char smem[30336];
  unsigned short* hj  = (unsigned short*)(smem);           // 32x136 bf16
  unsigned short* haj = (unsigned short*)(smem + 8704);    // 32x136 bf16
  unsigned short* hjt = (unsigned short*)(smem + 17408);   // 128x40 bf16
  unsigned short* pl  = (unsigned short*)(smem + 27648);   // 32x40  bf16
  float* co = (float*)(smem + 30208);                      // 32 f32

  const int t = threadIdx.x, w = t >> 6, lane = t & 63;
  const int q = lane >> 4, l15 = lane & 15;
  const int b = blockIdx.z, itile = blockIdx.x;
  const int ihalf = w >> 1, jhalf = w & 1, dgroup = w & 1;

  const size_t irowg = (size_t)b * N_ + itile * 32 + ihalf * 16 + l15;
  short8 ahai[4], ahi[4];
#pragma unroll
  for (int c = 0; c < 4; c++) {
    ahai[c] = *(const short8*)(hab + irowg * D_ + c * 32 + q * 8);
    ahi[c]  = *(const short8*)(hb  + irowg * D_ + c * 32 + q * 8);
  }
  f32x4 acc[4];
#pragma unroll
  for (int c = 0; c < 4; c++) acc[c] = (f32x4){0.f, 0.f, 0.f, 0.f};

  for (int jt = 0; jt < N_ / 32; jt++) {
    const int jbase = jt * 32;
    __syncthreads();
#pragma unroll
    for (int k = 0; k < 2; k++) {
      int s = t + 256 * k;
      int row = s >> 4, part = s & 15;
      size_t g = ((size_t)b * N_ + jbase + row) * D_ + part * 8;
      *(short8*)(hj  + row * 136 + part * 8) = *(const short8*)(hb + g);
      *(short8*)(haj + row * 136 + part * 8) = *(const short8*)(hab + g);
      int dd = s >> 2, p2 = s & 3;
      *(short8*)(hjt + dd * 40 + p2 * 8) =
          *(const short8*)(hbt + ((size_t)b * D_ + dd) * N_ + jbase + p2 * 8);
    }
    __syncthreads();
    f32x4 e = (f32x4){0.f, 0.f, 0.f, 0.f};
    const int brow = jhalf * 16 + l15;
#pragma unroll
    for (int c = 0; c < 4; c++) {
      short8 bh  = *(const short8*)(hj  + brow * 136 + c * 32 + q * 8);
      short8 bha = *(const short8*)(haj + brow * 136 + c * 32 + q * 8);
      e = __builtin_amdgcn_mfma_f32_16x16x32_bf16(ahai[c], bh,  e, 0, 0, 0);
      e = __builtin_amdgcn_mfma_f32_16x16x32_bf16(ahi[c],  bha, e, 0, 0, 0);
    }
    const float rs = 1.0f / s_in[(size_t)b * N_ + jbase + jhalf * 16 + l15];
#pragma unroll
    for (int r = 0; r < 4; r++) {
      int irow = itile * 32 + ihalf * 16 + q * 4 + r;
      unsigned int mb = bits[((size_t)b * N_ + irow) * (N_ / 32) + (jbase >> 5)];
      float p = ((mb >> (jhalf * 16 + l15)) & 1u)
                    ? __expf(fminf(e[r], 60.f)) * rs : 0.f;
      pl[(ihalf * 16 + q * 4 + r) * 40 + jhalf * 16 + l15] = f2bf(p);
    }
    __syncthreads();
    short8 ap = *(const short8*)(pl + (ihalf * 16 + l15) * 40 + q * 8);
#pragma unroll
    for (int c2 = 0; c2 < 4; c2++) {
      int dbase = dgroup * 64 + c2 * 16;
      short8 bv = *(const short8*)(hjt + (dbase + l15) * 40 + q * 8);
      acc[c2] = __builtin_amdgcn_mfma_f32_16x16x32_bf16(ap, bv, acc[c2], 0, 0, 0);
    }
  }
  __syncthreads();
  float* hp = (float*)smem;  // 32 x 132 f32, overlays hj/haj (16896 <= 17408)
#pragma unroll
  for (int c2 = 0; c2 < 4; c2++) {
    int dbase = dgroup * 64 + c2 * 16;
#pragma unroll
    for (int r = 0; r < 4; r++) {
      float v = acc[c2][r];
      hp[(ihalf * 16 + q * 4 + r) * 132 + dbase + l15] = v > 0.f ? v : 0.f;
    }
  }
  __syncthreads();
  {
    int grow = t >> 3, sub = t & 7;
    size_t xrow = ((size_t)b * N_ + itile * 32 + grow) * D_;
    float z = 0.f;
#pragma unroll
    for (int k = 0; k < 16; k++) {
      int dd = sub + 8 * k;
      z += gw[dd] * x[xrow + dd] + gw[128 + dd] * hp[grow * 132 + dd];
    }
    z += __shfl_xor(z, 1, 64);
    z += __shfl_xor(z, 2, 64);
    z += __shfl_xor(z, 4, 64);
    if (sub == 0) co[grow] = 1.f / (1.f + __expf(-(z + gb[0])));
  }
  __syncthreads();
#pragma unroll
  for (int k = 0; k < 16; k++) {
    int idx = k * 256 + t;
    int row = idx >> 7, col = idx & 127;
    size_t g = ((size_t)b * N_ + itile * 32 + row) * D_ + col;
    float cf = co[row];
    out[g] = cf * x[g] + (1.f - cf) * hp[row * 132 + col];
  }
}

extern "C" void kernel_launch(void* const* d_in, const int* in_sizes, int n_in,
                              void* d_out, int out_size, void* d_ws, size_t ws_size,
                              hipStream_t stream) {
  const float* x   = (const float*)d_in[0];
  const float* adj = (const float*)d_in[1];
  const float* Ww  = (const float*)d_in[2];
  const float* Wb  = (const float*)d_in[3];
  const float* A   = (const float*)d_in[4];
  const float* gw  = (const float*)d_in[5];
  const float* gb  = (const float*)d_in[6];
  float* out = (float*)d_out;
  char* ws = (char*)d_ws;

  unsigned short* hb   = (unsigned short*)(ws + HB_OFF);
  unsigned short* hab  = (unsigned short*)(ws + HAB_OFF);
  unsigned short* hbt  = (unsigned short*)(ws + HBT_OFF);
  unsigned long long* bits64 = (unsigned long long*)(ws + BITS_OFF);
  unsigned int* bits32 = (unsigned int*)(ws + BITS_OFF);
  float* s  = (float*)(ws + S_OFF);
  float* Wt = (float*)(ws + WT_OFF);

  hipMemsetAsync(s, 0, (size_t)B_ * N_ * sizeof(float), stream);
  k_wt<<<1, 256, 0, stream>>>(Ww, Wt);
  k_bits<<<(B_ * N_ * N_) / 256, 256, 0, stream>>>(adj, bits64);
  k1<<<(B_ * N_) / 8, 256, 0, stream>>>(x, Wt, Wb, A, hb, hab);
  k1t<<<dim3(N_ / 64, B_), 256, 0, stream>>>(hb, hbt);
  k2<<<dim3(N_ / 32, 4, B_), 256, 0, stream>>>(hb, hab, bits32, s);
  k3<<<dim3(N_ / 32, 1, B_), 256, 0, stream>>>(hb, hab, hbt, bits32, s, x, gw, gb, out);
}

// Round 2
// 391.817 us; speedup vs baseline: 1.2913x; 1.2913x over previous
//
#include <hip/hip_runtime.h>

// GAT_gate: B=8, N=2048, D=128
// out = c*x + (1-c)*relu(att@h), att = colsoftmax(mask(hA h^T + h hA^T))*adj
// e small (|e|<~6) -> exp without max-subtraction (clamp 60).
// cat[n][0:128]=hA[n], cat[n][128:256]=h[n]; e[i,j] = cat[i] . catsw[j]
// where catsw[j][c] = cat[j][(c+128)%256]  (single K=256 GEMM).
// k2: column sums s[k].  k3: fused E->P->PV with K-split PV (wave-private P,
// 2 barriers/iter), j-split over NPART partial buffers (d_out is partial 0).
// k4: sum partials, relu, gate, blend.

#define B_ 8
#define N_ 2048
#define D_ 128

typedef __attribute__((ext_vector_type(8))) short short8;
typedef __attribute__((ext_vector_type(4))) float f32x4;

#define GLL(gp, lp) __builtin_amdgcn_global_load_lds( \
    (__attribute__((address_space(1))) const unsigned int*)(gp), \
    (__attribute__((address_space(3))) unsigned int*)(lp), 16, 0, 0)

static __device__ __forceinline__ unsigned short f2bf(float f) {
  union { float f; unsigned int u; } v; v.f = f;
  unsigned int r = v.u + 0x7fffu + ((v.u >> 16) & 1u);
  return (unsigned short)(r >> 16);
}

// ---- workspace layout (bytes) ----
#define CAT_OFF  ((size_t)0)          // bf16 cat [B][N][256]      8 MB
#define HBT_OFF  ((size_t)8388608)    // bf16 h^T [B][128][N]      4 MB
#define BITS_OFF ((size_t)12582912)   // adj bitmask [B][N][N/64]  4 MB
#define S_OFF    ((size_t)16777216)   // f32 colsum s [B][N]       64 KB
#define WT_OFF   ((size_t)16842752)   // f32 W^T [128][128]        64 KB
#define PART_OFF ((size_t)16908288)   // f32 partials (NPART-1) x 8 MB
#define PART_SZ  ((size_t)8388608)

// ---------- prep: W transpose ----------
__global__ void k_wt(const float* __restrict__ W, float* __restrict__ Wt) {
  int t = threadIdx.x;
  for (int i = t; i < 128 * 128; i += 256) {
    int d = i >> 7, f = i & 127;
    Wt[f * 128 + d] = W[i];
  }
}

// ---------- prep: adj -> bitmask via ballot ----------
__global__ void k_bits(const float* __restrict__ adj,
                       unsigned long long* __restrict__ bits) {
  size_t i = (size_t)blockIdx.x * 256 + threadIdx.x;
  bool v = adj[i] > 0.0f;
  unsigned long long m = __ballot(v);
  if ((threadIdx.x & 63) == 0) bits[i >> 6] = m;
}

// ---------- prep: h = xW^T + b, hA = h@A ; write cat bf16 ----------
__global__ __launch_bounds__(256) void k1(const float* __restrict__ x,
                                          const float* __restrict__ Wt,
                                          const float* __restrict__ Wb,
                                          const float* __restrict__ A,
                                          unsigned short* __restrict__ cat) {
  __shared__ float xs[8][128];
  __shared__ float hs[8][128];
  const int t = threadIdx.x;
  const size_t rowbase = (size_t)blockIdx.x * 8;
  {
    int row = t >> 5, part = t & 31;
    *(f32x4*)&xs[row][part * 4] = *(const f32x4*)(x + (rowbase + row) * D_ + part * 4);
  }
  __syncthreads();
  const int d = t & 127, r2 = t >> 7;
  float a0 = 0, a1 = 0, a2 = 0, a3 = 0;
  for (int f = 0; f < 128; f++) {
    float wv = Wt[f * 128 + d];
    a0 += xs[r2 * 4 + 0][f] * wv;
    a1 += xs[r2 * 4 + 1][f] * wv;
    a2 += xs[r2 * 4 + 2][f] * wv;
    a3 += xs[r2 * 4 + 3][f] * wv;
  }
  float wb = Wb[d];
  a0 += wb; a1 += wb; a2 += wb; a3 += wb;
  hs[r2 * 4 + 0][d] = a0; hs[r2 * 4 + 1][d] = a1;
  hs[r2 * 4 + 2][d] = a2; hs[r2 * 4 + 3][d] = a3;
  cat[(rowbase + r2 * 4 + 0) * 256 + 128 + d] = f2bf(a0);
  cat[(rowbase + r2 * 4 + 1) * 256 + 128 + d] = f2bf(a1);
  cat[(rowbase + r2 * 4 + 2) * 256 + 128 + d] = f2bf(a2);
  cat[(rowbase + r2 * 4 + 3) * 256 + 128 + d] = f2bf(a3);
  __syncthreads();
  float b0 = 0, b1 = 0, b2 = 0, b3 = 0;
  for (int f = 0; f < 128; f++) {
    float av = A[f * 128 + d];
    b0 += hs[r2 * 4 + 0][f] * av;
    b1 += hs[r2 * 4 + 1][f] * av;
    b2 += hs[r2 * 4 + 2][f] * av;
    b3 += hs[r2 * 4 + 3][f] * av;
  }
  cat[(rowbase + r2 * 4 + 0) * 256 + d] = f2bf(b0);
  cat[(rowbase + r2 * 4 + 1) * 256 + d] = f2bf(b1);
  cat[(rowbase + r2 * 4 + 2) * 256 + d] = f2bf(b2);
  cat[(rowbase + r2 * 4 + 3) * 256 + d] = f2bf(b3);
}

// ---------- prep: hbt[b][d][n] = h[b][n][d] ----------
__global__ __launch_bounds__(256) void k1t(const unsigned short* __restrict__ cat,
                                           unsigned short* __restrict__ hbt) {
  __shared__ unsigned short tile[64][136];
  const int t = threadIdx.x;
  const int b = blockIdx.y;
  const int nbase = blockIdx.x * 64;
#pragma unroll
  for (int k = 0; k < 4; k++) {
    int s = t + 256 * k;
    int row = s >> 4, part = s & 15;
    *(short8*)&tile[row][part * 8] =
        *(const short8*)(cat + (((size_t)(b * N_ + nbase + row)) << 8) + 128 + part * 8);
  }
  __syncthreads();
#pragma unroll
  for (int k = 0; k < 4; k++) {
    int s = t + 256 * k;
    int dd = s >> 3, part = s & 7;
    unsigned short tmp[8];
#pragma unroll
    for (int j = 0; j < 8; j++) tmp[j] = tile[part * 8 + j][dd];
    *(short8*)(hbt + (((size_t)(b * 128 + dd)) << 11) + nbase + part * 8) = *(short8*)tmp;
  }
}

// ---------- k2: s[k] = sum_j adj[j,k]*exp(e[j,k]) ----------
// grid (N/128, 8, B); 4 waves; wave w owns k-cols [w*32, w*32+32)
__global__ __launch_bounds__(256, 3) void k2(const unsigned short* __restrict__ cat,
                                             const unsigned int* __restrict__ bits,
                                             float* __restrict__ s_out) {
  __shared__ unsigned short cj[64 * 256];  // 32 KB, XOR-swizzled chunks
  const int t = threadIdx.x, w = t >> 6, lane = t & 63;
  const int q = lane >> 4, l15 = lane & 15;
  const int b = blockIdx.z;
  const int kbase = blockIdx.x * 128;
  const int j0b = blockIdx.y * 256;
  const size_t bN = (size_t)b * N_;
  const unsigned short* catp = cat + (bN << 8);
  short8 brg[2][8];  // catsw_k fragments (swap = +16 chunks mod 32)
#pragma unroll
  for (int ksub = 0; ksub < 2; ksub++) {
    int krow = kbase + w * 32 + ksub * 16 + l15;
#pragma unroll
    for (int m = 0; m < 8; m++)
      brg[ksub][m] = *(const short8*)(catp + (((size_t)krow) << 8) +
                                      ((((m * 4 + q) + 16) & 31) * 8));
  }
  float acc0 = 0.f, acc1 = 0.f;
  for (int jt = 0; jt < 4; jt++) {
    const int j0 = j0b + jt * 64;
#pragma unroll
    for (int it = 0; it < 8; it++) {
      int sI = it * 256 + t;
      int row = sI >> 5, c = sI & 31;
      GLL(catp + (((size_t)(j0 + row)) << 8) + (c ^ (row & 7)) * 8,
          (char*)cj + sI * 16);
    }
    __syncthreads();
#pragma unroll
    for (int jsub = 0; jsub < 4; jsub++) {
      const int row = jsub * 16 + l15;
      short8 afr[8];
#pragma unroll
      for (int m = 0; m < 8; m++)
        afr[m] = *(short8*)(cj + row * 256 + (((m * 4 + q) ^ (l15 & 7)) * 8));
      f32x4 e0 = {0.f, 0.f, 0.f, 0.f}, e1 = {0.f, 0.f, 0.f, 0.f};
#pragma unroll
      for (int m = 0; m < 8; m++) {
        e0 = __builtin_amdgcn_mfma_f32_16x16x32_bf16(afr[m], brg[0][m], e0, 0, 0, 0);
        e1 = __builtin_amdgcn_mfma_f32_16x16x32_bf16(afr[m], brg[1][m], e1, 0, 0, 0);
      }
#pragma unroll
      for (int r = 0; r < 4; r++) {
        int jrow = j0 + jsub * 16 + q * 4 + r;
        unsigned int mb = bits[(bN + jrow) * 64 + (kbase >> 5) + w];
        float x0 = __expf(fminf(e0[r], 60.f));
        float x1 = __expf(fminf(e1[r], 60.f));
        if ((mb >> l15) & 1u) acc0 += x0;
        if ((mb >> (16 + l15)) & 1u) acc1 += x1;
      }
    }
    __syncthreads();
  }
  acc0 += __shfl_xor(acc0, 16, 64); acc0 += __shfl_xor(acc0, 32, 64);
  acc1 += __shfl_xor(acc1, 16, 64); acc1 += __shfl_xor(acc1, 32, 64);
  if (lane < 16) {
    atomicAdd(&s_out[bN + kbase + w * 32 + lane], acc0);
    atomicAdd(&s_out[bN + kbase + w * 32 + 16 + lane], acc1);
  }
}

// ---------- k3: fused E -> P -> PV (K-split), partial h' per j-range ----------
// grid (N/64, NPART, B); 4 waves: (ih=w>>1, jh=w&1). Wave owns i-rows
// ih*32..+32 and j-cols jh*32..+32 of each 64x64 tile; PV over own 32-j slice.
__global__ __launch_bounds__(256, 2) void k3(const unsigned short* __restrict__ cat,
                                             const unsigned short* __restrict__ hbt,
                                             const unsigned int* __restrict__ bits,
                                             const float* __restrict__ s_in,
                                             float* __restrict__ out,
                                             float* __restrict__ parts,
                                             int jspan) {
  __shared__ char smem[59392];
  // [0,32768): catsw_j 64x(32 chunks)  [32768,49152): hjt 128x(8 chunks)
  // [49152,59392): P 4 waves x 32x40 bf16
  const int t = threadIdx.x, w = t >> 6, lane = t & 63;
  const int q = lane >> 4, l15 = lane & 15;
  const int b = blockIdx.z, itile = blockIdx.x, p = blockIdx.y;
  const int ih = w >> 1, jh = w & 1;
  const int i0 = itile * 64;
  const size_t bN = (size_t)b * N_;
  const unsigned short* catp = cat + (bN << 8);
  const unsigned short* hbtp = hbt + (((size_t)b * 128) << 11);
  unsigned short* cs = (unsigned short*)smem;
  unsigned short* ht = (unsigned short*)(smem + 32768);
  unsigned short* pw = (unsigned short*)(smem + 49152) + w * 32 * 40;

  short8 ar[2][8];  // cat_i fragments (plain, no swap)
#pragma unroll
  for (int isub = 0; isub < 2; isub++)
#pragma unroll
    for (int m = 0; m < 8; m++)
      ar[isub][m] = *(const short8*)(catp +
          (((size_t)(i0 + ih * 32 + isub * 16 + l15)) << 8) + (m * 4 + q) * 8);

  f32x4 acc[2][8];
#pragma unroll
  for (int isub = 0; isub < 2; isub++)
#pragma unroll
    for (int dg = 0; dg < 8; dg++) acc[isub][dg] = (f32x4){0.f, 0.f, 0.f, 0.f};

  const int jbase0 = p * jspan;
  const int iters = jspan >> 6;
  for (int jt = 0; jt < iters; jt++) {
    const int j0 = jbase0 + jt * 64;
    // stage catsw (swap+swizzle) + hjt (swizzle), direct-to-LDS 16B
#pragma unroll
    for (int it = 0; it < 12; it++) {
      int sI = it * 256 + t;
      const unsigned short* g;
      if (sI < 2048) {
        int row = sI >> 5, c = sI & 31;
        int gc = ((c ^ (row & 7)) + 16) & 31;
        g = catp + (((size_t)(j0 + row)) << 8) + gc * 8;
      } else {
        int s2 = sI - 2048;
        int row = s2 >> 3, c = s2 & 7;
        g = hbtp + (((size_t)row) << 11) + j0 + (c ^ (row & 7)) * 8;
      }
      GLL(g, smem + sI * 16);
    }
    __syncthreads();
    // E phase + P (wave-private)
    float rsv0 = 1.f / s_in[bN + j0 + jh * 32 + l15];
    float rsv1 = 1.f / s_in[bN + j0 + jh * 32 + 16 + l15];
#pragma unroll
    for (int jsub = 0; jsub < 2; jsub++) {
      const int row = jh * 32 + jsub * 16 + l15;
      short8 bfr[8];
#pragma unroll
      for (int m = 0; m < 8; m++)
        bfr[m] = *(short8*)(cs + row * 256 + (((m * 4 + q) ^ (l15 & 7)) * 8));
      const float rs = jsub ? rsv1 : rsv0;
#pragma unroll
      for (int isub = 0; isub < 2; isub++) {
        f32x4 e = {0.f, 0.f, 0.f, 0.f};
#pragma unroll
        for (int m = 0; m < 8; m++)
          e = __builtin_amdgcn_mfma_f32_16x16x32_bf16(ar[isub][m], bfr[m], e, 0, 0, 0);
#pragma unroll
        for (int r = 0; r < 4; r++) {
          int irow = i0 + ih * 32 + isub * 16 + q * 4 + r;
          unsigned int mb = bits[(bN + irow) * 64 + (j0 >> 5) + jh];
          float pv = ((mb >> (jsub * 16 + l15)) & 1u)
                         ? __expf(fminf(e[r], 60.f)) * rs : 0.f;
          pw[(isub * 16 + q * 4 + r) * 40 + jsub * 16 + l15] = f2bf(pv);
        }
      }
    }
    // PV over own 32-j slice (no barrier needed: P is wave-private)
    short8 pa0 = *(short8*)(pw + l15 * 40 + q * 8);
    short8 pa1 = *(short8*)(pw + (16 + l15) * 40 + q * 8);
#pragma unroll
    for (int dg = 0; dg < 8; dg++) {
      short8 bv = *(short8*)(ht + (dg * 16 + l15) * 64 +
                             (((jh * 4 + q) ^ (l15 & 7)) * 8));
      acc[0][dg] = __builtin_amdgcn_mfma_f32_16x16x32_bf16(pa0, bv, acc[0][dg], 0, 0, 0);
      acc[1][dg] = __builtin_amdgcn_mfma_f32_16x16x32_bf16(pa1, bv, acc[1][dg], 0, 0, 0);
    }
    __syncthreads();
  }
  // epilogue: reduce jh pair via LDS (f32, stride 132), then coalesced store
  float* lf = (float*)smem;  // 2 regions x 32 x 132 f32 = 33792 B
  if (jh == 1) {
#pragma unroll
    for (int isub = 0; isub < 2; isub++)
#pragma unroll
      for (int dg = 0; dg < 8; dg++)
#pragma unroll
        for (int r = 0; r < 4; r++)
          lf[ih * 4224 + (isub * 16 + q * 4 + r) * 132 + dg * 16 + l15] =
              acc[isub][dg][r];
  }
  __syncthreads();
  if (jh == 0) {
#pragma unroll
    for (int isub = 0; isub < 2; isub++)
#pragma unroll
      for (int dg = 0; dg < 8; dg++)
#pragma unroll
        for (int r = 0; r < 4; r++)
          lf[ih * 4224 + (isub * 16 + q * 4 + r) * 132 + dg * 16 + l15] +=
              acc[isub][dg][r];
  }
  __syncthreads();
  float* dst = (p == 0) ? out : (parts + (size_t)(p - 1) * (PART_SZ / 4));
#pragma unroll
  for (int kk = 0; kk < 8; kk++) {
    int idx = kk * 256 + t;
    int rowi = idx >> 5, c4 = idx & 31;
    f32x4 v = *(f32x4*)(lf + (rowi >> 5) * 4224 + (rowi & 31) * 132 + c4 * 4);
    *(f32x4*)(dst + (((size_t)(bN + i0 + rowi)) << 7) + c4 * 4) = v;
  }
}

// ---------- k4: sum partials, relu, gate, blend ----------
__global__ __launch_bounds__(256) void k4(const float* __restrict__ x,
                                          const float* __restrict__ gw,
                                          const float* __restrict__ gb,
                                          float* __restrict__ out,
                                          const float* __restrict__ parts,
                                          int npart) {
  const int t = threadIdx.x, w = t >> 6, lane = t & 63;
  const size_t row = (size_t)blockIdx.x * 4 + w;
  const size_t base = (row << 7) + lane * 2;
  float2 xv = *(const float2*)(x + base);
  float2 hv = *(const float2*)(out + base);
  for (int p = 1; p < npart; p++) {
    float2 pv = *(const float2*)(parts + (size_t)(p - 1) * (PART_SZ / 4) + base);
    hv.x += pv.x; hv.y += pv.y;
  }
  hv.x = fmaxf(hv.x, 0.f); hv.y = fmaxf(hv.y, 0.f);
  const int d = lane * 2;
  float z = gw[d] * xv.x + gw[d + 1] * xv.y + gw[128 + d] * hv.x + gw[129 + d] * hv.y;
  z += __shfl_xor(z, 1, 64);
  z += __shfl_xor(z, 2, 64);
  z += __shfl_xor(z, 4, 64);
  z += __shfl_xor(z, 8, 64);
  z += __shfl_xor(z, 16, 64);
  z += __shfl_xor(z, 32, 64);
  float c = 1.f / (1.f + __expf(-(z + gb[0])));
  float2 o;
  o.x = c * xv.x + (1.f - c) * hv.x;
  o.y = c * xv.y + (1.f - c) * hv.y;
  *(float2*)(out + base) = o;
}

extern "C" void kernel_launch(void* const* d_in, const int* in_sizes, int n_in,
                              void* d_out, int out_size, void* d_ws, size_t ws_size,
                              hipStream_t stream) {
  const float* x   = (const float*)d_in[0];
  const float* adj = (const float*)d_in[1];
  const float* Ww  = (const float*)d_in[2];
  const float* Wb  = (const float*)d_in[3];
  const float* A   = (const float*)d_in[4];
  const float* gw  = (const float*)d_in[5];
  const float* gb  = (const float*)d_in[6];
  float* out = (float*)d_out;
  char* ws = (char*)d_ws;

  unsigned short* cat = (unsigned short*)(ws + CAT_OFF);
  unsigned short* hbt = (unsigned short*)(ws + HBT_OFF);
  unsigned long long* bits64 = (unsigned long long*)(ws + BITS_OFF);
  unsigned int* bits32 = (unsigned int*)(ws + BITS_OFF);
  float* s  = (float*)(ws + S_OFF);
  float* Wt = (float*)(ws + WT_OFF);
  float* parts = (float*)(ws + PART_OFF);

  int npart = 1;
  if (ws_size >= PART_OFF + 3 * PART_SZ) npart = 4;
  else if (ws_size >= PART_OFF + 1 * PART_SZ) npart = 2;
  const int jspan = N_ / npart;

  hipMemsetAsync(s, 0, (size_t)B_ * N_ * sizeof(float), stream);
  k_wt<<<1, 256, 0, stream>>>(Ww, Wt);
  k_bits<<<(B_ * N_ * N_) / 256, 256, 0, stream>>>(adj, bits64);
  k1<<<(B_ * N_) / 8, 256, 0, stream>>>(x, Wt, Wb, A, cat);
  k1t<<<dim3(N_ / 64, B_), 256, 0, stream>>>(cat, hbt);
  k2<<<dim3(N_ / 128, 8, B_), 256, 0, stream>>>(cat, bits32, s);
  k3<<<dim3(N_ / 64, npart, B_), 256, 0, stream>>>(cat, hbt, bits32, s, out, parts, jspan);
  k4<<<B_ * N_ / 4, 256, 0, stream>>>(x, gw, gb, out, parts, npart);
}

// Round 3
// 313.058 us; speedup vs baseline: 1.6162x; 1.2516x over previous
//
#include <hip/hip_runtime.h>

// GAT_gate: B=8, N=2048, D=128
// out = c*x + (1-c)*relu(att@h), att = colsoftmax(mask(hA h^T + h hA^T))*adj
// e small (|e|<~6) -> exp without max-subtraction (clamp 60).
// cat[n][0:128]=hA[n], cat[n][128:256]=h[n]; e[i,j] = cat[i] . catsw[j].
// k2: computes E once, masks with RAW adj (single HBM pass of adj, no k_bits),
//     accumulates column sums s[k], and materializes P_un = adj*exp(E) bf16.
// k1v: vt[d][j] = bf16(h[j][d] / s[j])  (folds softmax denom into V).
// k3: pure GEMM h' = P_un @ V' + fused relu/gate/sigmoid/blend epilogue.

#define B_ 8
#define N_ 2048
#define D_ 128

typedef __attribute__((ext_vector_type(8))) short short8;
typedef __attribute__((ext_vector_type(4))) float f32x4;

#define GLL(gp, lp) __builtin_amdgcn_global_load_lds( \
    (__attribute__((address_space(1))) const unsigned int*)(gp), \
    (__attribute__((address_space(3))) unsigned int*)(lp), 16, 0, 0)

static __device__ __forceinline__ unsigned short f2bf(float f) {
  union { float f; unsigned int u; } v; v.f = f;
  unsigned int r = v.u + 0x7fffu + ((v.u >> 16) & 1u);
  return (unsigned short)(r >> 16);
}
static __device__ __forceinline__ float bf2f(unsigned short u) {
  union { unsigned int u; float f; } v; v.u = ((unsigned int)u) << 16;
  return v.f;
}

// ---- workspace layout (bytes) ----
#define CAT_OFF ((size_t)0)         // bf16 cat [B][N][256]        8 MB
#define VT_OFF  ((size_t)8388608)   // bf16 V'^T [B][128][N]       4 MB
#define PUN_OFF ((size_t)12582912)  // bf16 P_un [B][N][N]         67.1 MB
#define S_OFF   ((size_t)79691776)  // f32 colsum s [B][N]         64 KB
#define WT_OFF  ((size_t)79757312)  // f32 W^T [128][128]          64 KB

// ---------- prep: W transpose ----------
__global__ void k_wt(const float* __restrict__ W, float* __restrict__ Wt) {
  int t = threadIdx.x;
  for (int i = t; i < 128 * 128; i += 256) {
    int d = i >> 7, f = i & 127;
    Wt[f * 128 + d] = W[i];
  }
}

// ---------- prep: h = xW^T + b, hA = h@A ; write cat bf16 ----------
__global__ __launch_bounds__(256) void k1(const float* __restrict__ x,
                                          const float* __restrict__ Wt,
                                          const float* __restrict__ Wb,
                                          const float* __restrict__ A,
                                          unsigned short* __restrict__ cat) {
  __shared__ float xs[8][128];
  __shared__ float hs[8][128];
  const int t = threadIdx.x;
  const size_t rowbase = (size_t)blockIdx.x * 8;
  {
    int row = t >> 5, part = t & 31;
    *(f32x4*)&xs[row][part * 4] = *(const f32x4*)(x + (rowbase + row) * D_ + part * 4);
  }
  __syncthreads();
  const int d = t & 127, r2 = t >> 7;
  float a0 = 0, a1 = 0, a2 = 0, a3 = 0;
  for (int f = 0; f < 128; f++) {
    float wv = Wt[f * 128 + d];
    a0 += xs[r2 * 4 + 0][f] * wv;
    a1 += xs[r2 * 4 + 1][f] * wv;
    a2 += xs[r2 * 4 + 2][f] * wv;
    a3 += xs[r2 * 4 + 3][f] * wv;
  }
  float wb = Wb[d];
  a0 += wb; a1 += wb; a2 += wb; a3 += wb;
  hs[r2 * 4 + 0][d] = a0; hs[r2 * 4 + 1][d] = a1;
  hs[r2 * 4 + 2][d] = a2; hs[r2 * 4 + 3][d] = a3;
  cat[(rowbase + r2 * 4 + 0) * 256 + 128 + d] = f2bf(a0);
  cat[(rowbase + r2 * 4 + 1) * 256 + 128 + d] = f2bf(a1);
  cat[(rowbase + r2 * 4 + 2) * 256 + 128 + d] = f2bf(a2);
  cat[(rowbase + r2 * 4 + 3) * 256 + 128 + d] = f2bf(a3);
  __syncthreads();
  float b0 = 0, b1 = 0, b2 = 0, b3 = 0;
  for (int f = 0; f < 128; f++) {
    float av = A[f * 128 + d];
    b0 += hs[r2 * 4 + 0][f] * av;
    b1 += hs[r2 * 4 + 1][f] * av;
    b2 += hs[r2 * 4 + 2][f] * av;
    b3 += hs[r2 * 4 + 3][f] * av;
  }
  cat[(rowbase + r2 * 4 + 0) * 256 + d] = f2bf(b0);
  cat[(rowbase + r2 * 4 + 1) * 256 + d] = f2bf(b1);
  cat[(rowbase + r2 * 4 + 2) * 256 + d] = f2bf(b2);
  cat[(rowbase + r2 * 4 + 3) * 256 + d] = f2bf(b3);
}

// ---------- k2: E once; s[k] += adj*exp(E); P_un = adj*exp(E) bf16 ----------
// grid (N/128, 8, B); 4 waves; wave w owns k-cols [w*32, w*32+32)
__global__ __launch_bounds__(256, 3) void k2(const unsigned short* __restrict__ cat,
                                             const float* __restrict__ adj,
                                             unsigned short* __restrict__ pun,
                                             float* __restrict__ s_out) {
  __shared__ unsigned short cj[64 * 256];  // 32 KB, XOR-swizzled chunks
  const int t = threadIdx.x, w = t >> 6, lane = t & 63;
  const int q = lane >> 4, l15 = lane & 15;
  const int b = blockIdx.z;
  const int kbase = blockIdx.x * 128;
  const int j0b = blockIdx.y * 256;
  const size_t bN = (size_t)b * N_;
  const unsigned short* catp = cat + (bN << 8);
  short8 brg[2][8];  // catsw_k fragments (swap = +16 chunks mod 32)
#pragma unroll
  for (int ksub = 0; ksub < 2; ksub++) {
    int krow = kbase + w * 32 + ksub * 16 + l15;
#pragma unroll
    for (int m = 0; m < 8; m++)
      brg[ksub][m] = *(const short8*)(catp + (((size_t)krow) << 8) +
                                      ((((m * 4 + q) + 16) & 31) * 8));
  }
  const int kc = kbase + w * 32;
  float acc0 = 0.f, acc1 = 0.f;
  for (int jt = 0; jt < 4; jt++) {
    const int j0 = j0b + jt * 64;
#pragma unroll
    for (int it = 0; it < 8; it++) {
      int sI = it * 256 + t;
      int row = sI >> 5, c = sI & 31;
      GLL(catp + (((size_t)(j0 + row)) << 8) + (c ^ (row & 7)) * 8,
          (char*)cj + sI * 16);
    }
    __syncthreads();
#pragma unroll
    for (int jsub = 0; jsub < 4; jsub++) {
      const int row = jsub * 16 + l15;
      short8 afr[8];
#pragma unroll
      for (int m = 0; m < 8; m++)
        afr[m] = *(short8*)(cj + row * 256 + (((m * 4 + q) ^ (l15 & 7)) * 8));
      f32x4 e0 = {0.f, 0.f, 0.f, 0.f}, e1 = {0.f, 0.f, 0.f, 0.f};
#pragma unroll
      for (int m = 0; m < 8; m++) {
        e0 = __builtin_amdgcn_mfma_f32_16x16x32_bf16(afr[m], brg[0][m], e0, 0, 0, 0);
        e1 = __builtin_amdgcn_mfma_f32_16x16x32_bf16(afr[m], brg[1][m], e1, 0, 0, 0);
      }
#pragma unroll
      for (int r = 0; r < 4; r++) {
        int jrow = j0 + jsub * 16 + q * 4 + r;
        size_t rowoff = ((size_t)(bN + jrow)) << 11;
        float av0 = adj[rowoff + kc + l15];
        float av1 = adj[rowoff + kc + 16 + l15];
        float ex0 = __expf(fminf(e0[r], 60.f));
        float ex1 = __expf(fminf(e1[r], 60.f));
        float x0 = av0 > 0.f ? ex0 : 0.f;
        float x1 = av1 > 0.f ? ex1 : 0.f;
        acc0 += x0; acc1 += x1;
        pun[rowoff + kc + l15] = f2bf(x0);
        pun[rowoff + kc + 16 + l15] = f2bf(x1);
      }
    }
    __syncthreads();
  }
  acc0 += __shfl_xor(acc0, 16, 64); acc0 += __shfl_xor(acc0, 32, 64);
  acc1 += __shfl_xor(acc1, 16, 64); acc1 += __shfl_xor(acc1, 32, 64);
  if (lane < 16) {
    atomicAdd(&s_out[bN + kc + lane], acc0);
    atomicAdd(&s_out[bN + kc + 16 + lane], acc1);
  }
}

// ---------- k1v: vt[b][d][j] = bf16(h[b][j][d] / s[j]) ----------
__global__ __launch_bounds__(256) void k1v(const unsigned short* __restrict__ cat,
                                           const float* __restrict__ s,
                                           unsigned short* __restrict__ vt) {
  __shared__ unsigned short tile[64][136];
  __shared__ float rsv[64];
  const int t = threadIdx.x;
  const int b = blockIdx.y;
  const int nbase = blockIdx.x * 64;
  if (t < 64) rsv[t] = 1.f / s[(size_t)b * N_ + nbase + t];
#pragma unroll
  for (int k = 0; k < 4; k++) {
    int sI = t + 256 * k;
    int row = sI >> 4, part = sI & 15;
    *(short8*)&tile[row][part * 8] =
        *(const short8*)(cat + (((size_t)(b * N_ + nbase + row)) << 8) + 128 + part * 8);
  }
  __syncthreads();
#pragma unroll
  for (int k = 0; k < 4; k++) {
    int sI = t + 256 * k;
    int dd = sI >> 3, part = sI & 7;
    unsigned short tmp[8];
#pragma unroll
    for (int j = 0; j < 8; j++) {
      int jj = part * 8 + j;
      tmp[j] = f2bf(bf2f(tile[jj][dd]) * rsv[jj]);
    }
    *(short8*)(vt + (((size_t)(b * 128 + dd)) << 11) + nbase + part * 8) = *(short8*)tmp;
  }
}

// ---------- k3: h' = P_un @ V'; out = c*x + (1-c)*relu(h') ----------
// grid (N/32, B); 4 waves; wave w owns d-group [w*32, w*32+32)
__global__ __launch_bounds__(256) void k3(const unsigned short* __restrict__ pun,
                                          const unsigned short* __restrict__ vt,
                                          const float* __restrict__ x,
                                          const float* __restrict__ gw,
                                          const float* __restrict__ gb,
                                          float* __restrict__ out) {
  __shared__ char smem[20480];
  // [0,4096): A-tile P_un 32 x 64j  [4096,20480): B-tile vt 128d x 64j
  const int t = threadIdx.x, w = t >> 6, lane = t & 63;
  const int q = lane >> 4, l15 = lane & 15;
  const int b = blockIdx.y, i0 = blockIdx.x * 32;
  const size_t bN = (size_t)b * N_;
  unsigned short* pa = (unsigned short*)smem;
  unsigned short* vb = (unsigned short*)(smem + 4096);

  f32x4 acc[2][2];
#pragma unroll
  for (int ih = 0; ih < 2; ih++)
#pragma unroll
    for (int dh = 0; dh < 2; dh++) acc[ih][dh] = (f32x4){0.f, 0.f, 0.f, 0.f};

  for (int jt = 0; jt < N_ / 64; jt++) {
    const int j0 = jt * 64;
#pragma unroll
    for (int it = 0; it < 5; it++) {
      int sI = it * 256 + t;
      const unsigned short* g;
      if (sI < 256) {
        int row = sI >> 3, c = sI & 7;
        g = pun + (((size_t)(bN + i0 + row)) << 11) + j0 + ((c ^ (row & 7)) * 8);
      } else {
        int s2 = sI - 256;
        int dd = s2 >> 3, c = s2 & 7;
        g = vt + (((size_t)(b * 128 + dd)) << 11) + j0 + ((c ^ (dd & 7)) * 8);
      }
      GLL(g, smem + sI * 16);
    }
    __syncthreads();
#pragma unroll
    for (int ks = 0; ks < 2; ks++) {
      short8 af[2], bf[2];
#pragma unroll
      for (int ih = 0; ih < 2; ih++) {
        int m = ih * 16 + l15;
        af[ih] = *(short8*)(pa + m * 64 + (((ks * 4 + q) ^ (m & 7)) * 8));
      }
#pragma unroll
      for (int dh = 0; dh < 2; dh++) {
        int d = w * 32 + dh * 16 + l15;
        bf[dh] = *(short8*)(vb + d * 64 + (((ks * 4 + q) ^ (d & 7)) * 8));
      }
      acc[0][0] = __builtin_amdgcn_mfma_f32_16x16x32_bf16(af[0], bf[0], acc[0][0], 0, 0, 0);
      acc[0][1] = __builtin_amdgcn_mfma_f32_16x16x32_bf16(af[0], bf[1], acc[0][1], 0, 0, 0);
      acc[1][0] = __builtin_amdgcn_mfma_f32_16x16x32_bf16(af[1], bf[0], acc[1][0], 0, 0, 0);
      acc[1][1] = __builtin_amdgcn_mfma_f32_16x16x32_bf16(af[1], bf[1], acc[1][1], 0, 0, 0);
    }
    __syncthreads();
  }
  // epilogue: relu -> LDS f32, gate, sigmoid, blend, store
  float* hs = (float*)smem;            // 32 x 132 f32 = 16896 B
  float* co = (float*)(smem + 16896);  // 32 f32
#pragma unroll
  for (int ih = 0; ih < 2; ih++)
#pragma unroll
    for (int dh = 0; dh < 2; dh++)
#pragma unroll
      for (int r = 0; r < 4; r++) {
        int row = ih * 16 + q * 4 + r;
        int d = w * 32 + dh * 16 + l15;
        hs[row * 132 + d] = fmaxf(acc[ih][dh][r], 0.f);
      }
  __syncthreads();
  {
    int grow = t >> 3, sub = t & 7;
    const float* xr = x + (((size_t)(bN + i0 + grow)) << 7);
    float z = 0.f;
#pragma unroll
    for (int k = 0; k < 16; k++) {
      int dd = sub + 8 * k;
      z += gw[dd] * xr[dd] + gw[128 + dd] * hs[grow * 132 + dd];
    }
    z += __shfl_xor(z, 1, 64);
    z += __shfl_xor(z, 2, 64);
    z += __shfl_xor(z, 4, 64);
    if (sub == 0) co[grow] = 1.f / (1.f + __expf(-(z + gb[0])));
  }
  __syncthreads();
#pragma unroll
  for (int kk = 0; kk < 4; kk++) {
    int id = kk * 256 + t;
    int row = id >> 5, c4 = id & 31;
    size_t g = (((size_t)(bN + i0 + row)) << 7) + c4 * 4;
    f32x4 xv = *(const f32x4*)(x + g);
    f32x4 hv = *(const f32x4*)(hs + row * 132 + c4 * 4);
    float cf = co[row];
    f32x4 o;
#pragma unroll
    for (int e = 0; e < 4; e++) o[e] = cf * xv[e] + (1.f - cf) * hv[e];
    *(f32x4*)(out + g) = o;
  }
}

extern "C" void kernel_launch(void* const* d_in, const int* in_sizes, int n_in,
                              void* d_out, int out_size, void* d_ws, size_t ws_size,
                              hipStream_t stream) {
  const float* x   = (const float*)d_in[0];
  const float* adj = (const float*)d_in[1];
  const float* Ww  = (const float*)d_in[2];
  const float* Wb  = (const float*)d_in[3];
  const float* A   = (const float*)d_in[4];
  const float* gw  = (const float*)d_in[5];
  const float* gb  = (const float*)d_in[6];
  float* out = (float*)d_out;
  char* ws = (char*)d_ws;

  unsigned short* cat = (unsigned short*)(ws + CAT_OFF);
  unsigned short* vt  = (unsigned short*)(ws + VT_OFF);
  unsigned short* pun = (unsigned short*)(ws + PUN_OFF);
  float* s  = (float*)(ws + S_OFF);
  float* Wt = (float*)(ws + WT_OFF);

  hipMemsetAsync(s, 0, (size_t)B_ * N_ * sizeof(float), stream);
  k_wt<<<1, 256, 0, stream>>>(Ww, Wt);
  k1<<<(B_ * N_) / 8, 256, 0, stream>>>(x, Wt, Wb, A, cat);
  k2<<<dim3(N_ / 128, 8, B_), 256, 0, stream>>>(cat, adj, pun, s);
  k1v<<<dim3(N_ / 64, B_), 256, 0, stream>>>(cat, s, vt);
  k3<<<dim3(N_ / 32, B_), 256, 0, stream>>>(pun, vt, x, gw, gb, out);
}

// Round 4
// 309.966 us; speedup vs baseline: 1.6323x; 1.0100x over previous
//
#include <hip/hip_runtime.h>

// GAT_gate: B=8, N=2048, D=128
// out = c*x + (1-c)*relu(att@h), att = colsoftmax(mask(hA h^T + h hA^T))*adj
// e small (|e|<~6) -> exp without max-subtraction (clamp 60).
// cat[n][0:128]=hA[n], cat[n][128:256]=h[n]; e[i,j] = cat[i] . catsw[j].
// k2: E once; mask from RAW adj (adj crosses HBM once); col-sums s[k];
//     P_un = adj*exp(E) stored bf16 PACKED-PAIR (wave owns k-cols 2*l15,2*l15+1
//     -> float2 adj loads, 4B packed pun stores).
// k1v: vt[d][j] = bf16(h[j][d] / s[j])  (softmax denom folded into V).
// k3: h' = P_un @ V' (32i x 128d block, j-tile 128, 16 MFMA/wave/barrier)
//     + fused relu/gate/sigmoid/blend epilogue.

#define B_ 8
#define N_ 2048
#define D_ 128

typedef __attribute__((ext_vector_type(8))) short short8;
typedef __attribute__((ext_vector_type(4))) float f32x4;

#define GLL(gp, lp) __builtin_amdgcn_global_load_lds( \
    (__attribute__((address_space(1))) const unsigned int*)(gp), \
    (__attribute__((address_space(3))) unsigned int*)(lp), 16, 0, 0)

static __device__ __forceinline__ unsigned short f2bf(float f) {
  union { float f; unsigned int u; } v; v.f = f;
  unsigned int r = v.u + 0x7fffu + ((v.u >> 16) & 1u);
  return (unsigned short)(r >> 16);
}
static __device__ __forceinline__ float bf2f(unsigned short u) {
  union { unsigned int u; float f; } v; v.u = ((unsigned int)u) << 16;
  return v.f;
}

// ---- workspace layout (bytes) ----
#define CAT_OFF ((size_t)0)         // bf16 cat [B][N][256]        8 MB
#define VT_OFF  ((size_t)8388608)   // bf16 V'^T [B][128][N]       4 MB
#define PUN_OFF ((size_t)12582912)  // bf16 P_un [B][N][N]         67.1 MB
#define S_OFF   ((size_t)79691776)  // f32 colsum s [B][N]         64 KB
#define WT_OFF  ((size_t)79757312)  // f32 W^T [128][128]          64 KB

// ---------- prep: W transpose ----------
__global__ void k_wt(const float* __restrict__ W, float* __restrict__ Wt) {
  int t = threadIdx.x;
  for (int i = t; i < 128 * 128; i += 256) {
    int d = i >> 7, f = i & 127;
    Wt[f * 128 + d] = W[i];
  }
}

// ---------- prep: h = xW^T + b, hA = h@A ; write cat bf16 ----------
__global__ __launch_bounds__(256) void k1(const float* __restrict__ x,
                                          const float* __restrict__ Wt,
                                          const float* __restrict__ Wb,
                                          const float* __restrict__ A,
                                          unsigned short* __restrict__ cat) {
  __shared__ float xs[8][128];
  __shared__ float hs[8][128];
  const int t = threadIdx.x;
  const size_t rowbase = (size_t)blockIdx.x * 8;
  {
    int row = t >> 5, part = t & 31;
    *(f32x4*)&xs[row][part * 4] = *(const f32x4*)(x + (rowbase + row) * D_ + part * 4);
  }
  __syncthreads();
  const int d = t & 127, r2 = t >> 7;
  float a0 = 0, a1 = 0, a2 = 0, a3 = 0;
  for (int f = 0; f < 128; f++) {
    float wv = Wt[f * 128 + d];
    a0 += xs[r2 * 4 + 0][f] * wv;
    a1 += xs[r2 * 4 + 1][f] * wv;
    a2 += xs[r2 * 4 + 2][f] * wv;
    a3 += xs[r2 * 4 + 3][f] * wv;
  }
  float wb = Wb[d];
  a0 += wb; a1 += wb; a2 += wb; a3 += wb;
  hs[r2 * 4 + 0][d] = a0; hs[r2 * 4 + 1][d] = a1;
  hs[r2 * 4 + 2][d] = a2; hs[r2 * 4 + 3][d] = a3;
  cat[(rowbase + r2 * 4 + 0) * 256 + 128 + d] = f2bf(a0);
  cat[(rowbase + r2 * 4 + 1) * 256 + 128 + d] = f2bf(a1);
  cat[(rowbase + r2 * 4 + 2) * 256 + 128 + d] = f2bf(a2);
  cat[(rowbase + r2 * 4 + 3) * 256 + 128 + d] = f2bf(a3);
  __syncthreads();
  float b0 = 0, b1 = 0, b2 = 0, b3 = 0;
  for (int f = 0; f < 128; f++) {
    float av = A[f * 128 + d];
    b0 += hs[r2 * 4 + 0][f] * av;
    b1 += hs[r2 * 4 + 1][f] * av;
    b2 += hs[r2 * 4 + 2][f] * av;
    b3 += hs[r2 * 4 + 3][f] * av;
  }
  cat[(rowbase + r2 * 4 + 0) * 256 + d] = f2bf(b0);
  cat[(rowbase + r2 * 4 + 1) * 256 + d] = f2bf(b1);
  cat[(rowbase + r2 * 4 + 2) * 256 + d] = f2bf(b2);
  cat[(rowbase + r2 * 4 + 3) * 256 + d] = f2bf(b3);
}

// ---------- k2: E once; s[k] += adj*exp(E); P_un packed-pair bf16 ----------
// grid (N/128, 16, B); 4 waves; wave w owns k-cols [w*32, w*32+32),
// lane's two accum cols are kc+2*l15 and kc+2*l15+1 (adjacent pair).
__global__ __launch_bounds__(256, 3) void k2(const unsigned short* __restrict__ cat,
                                             const float* __restrict__ adj,
                                             unsigned short* __restrict__ pun,
                                             float* __restrict__ s_out) {
  __shared__ unsigned short cj[64 * 256];  // 32 KB, XOR-swizzled chunks
  const int t = threadIdx.x, w = t >> 6, lane = t & 63;
  const int q = lane >> 4, l15 = lane & 15;
  const int b = blockIdx.z;
  const int kbase = blockIdx.x * 128;
  const int j0b = blockIdx.y * 128;
  const size_t bN = (size_t)b * N_;
  const unsigned short* catp = cat + (bN << 8);
  const int kc = kbase + w * 32;
  short8 brg[2][8];  // catsw_k fragments for k-cols kc+2*l15+p (swap +16 mod 32)
#pragma unroll
  for (int p = 0; p < 2; p++) {
    int krow = kc + 2 * l15 + p;
#pragma unroll
    for (int m = 0; m < 8; m++)
      brg[p][m] = *(const short8*)(catp + (((size_t)krow) << 8) +
                                   ((((m * 4 + q) + 16) & 31) * 8));
  }
  float acc0 = 0.f, acc1 = 0.f;
  for (int jt = 0; jt < 2; jt++) {
    const int j0 = j0b + jt * 64;
#pragma unroll
    for (int it = 0; it < 8; it++) {
      int sI = it * 256 + t;
      int row = sI >> 5, c = sI & 31;
      GLL(catp + (((size_t)(j0 + row)) << 8) + (c ^ (row & 7)) * 8,
          (char*)cj + sI * 16);
    }
    __syncthreads();
#pragma unroll
    for (int jsub = 0; jsub < 4; jsub++) {
      // adj prefetch (independent of MFMA results)
      float2 av[4];
#pragma unroll
      for (int r = 0; r < 4; r++) {
        int jrow = j0 + jsub * 16 + q * 4 + r;
        av[r] = *(const float2*)(adj + (((size_t)(bN + jrow)) << 11) + kc + 2 * l15);
      }
      const int row = jsub * 16 + l15;
      short8 afr[8];
#pragma unroll
      for (int m = 0; m < 8; m++)
        afr[m] = *(short8*)(cj + row * 256 + (((m * 4 + q) ^ (l15 & 7)) * 8));
      f32x4 e0 = {0.f, 0.f, 0.f, 0.f}, e1 = {0.f, 0.f, 0.f, 0.f};
#pragma unroll
      for (int m = 0; m < 8; m++) {
        e0 = __builtin_amdgcn_mfma_f32_16x16x32_bf16(afr[m], brg[0][m], e0, 0, 0, 0);
        e1 = __builtin_amdgcn_mfma_f32_16x16x32_bf16(afr[m], brg[1][m], e1, 0, 0, 0);
      }
#pragma unroll
      for (int r = 0; r < 4; r++) {
        int jrow = j0 + jsub * 16 + q * 4 + r;
        float x0 = av[r].x > 0.f ? __expf(fminf(e0[r], 60.f)) : 0.f;
        float x1 = av[r].y > 0.f ? __expf(fminf(e1[r], 60.f)) : 0.f;
        acc0 += x0; acc1 += x1;
        unsigned int pk = (unsigned int)f2bf(x0) | ((unsigned int)f2bf(x1) << 16);
        *(unsigned int*)(pun + (((size_t)(bN + jrow)) << 11) + kc + 2 * l15) = pk;
      }
    }
    __syncthreads();
  }
  acc0 += __shfl_xor(acc0, 16, 64); acc0 += __shfl_xor(acc0, 32, 64);
  acc1 += __shfl_xor(acc1, 16, 64); acc1 += __shfl_xor(acc1, 32, 64);
  if (lane < 16) {
    atomicAdd(&s_out[bN + kc + 2 * lane], acc0);
    atomicAdd(&s_out[bN + kc + 2 * lane + 1], acc1);
  }
}

// ---------- k1v: vt[b][d][j] = bf16(h[b][j][d] / s[j]) ----------
__global__ __launch_bounds__(256) void k1v(const unsigned short* __restrict__ cat,
                                           const float* __restrict__ s,
                                           unsigned short* __restrict__ vt) {
  __shared__ unsigned short tile[64][136];
  __shared__ float rsv[64];
  const int t = threadIdx.x;
  const int b = blockIdx.y;
  const int nbase = blockIdx.x * 64;
  if (t < 64) rsv[t] = 1.f / s[(size_t)b * N_ + nbase + t];
#pragma unroll
  for (int k = 0; k < 4; k++) {
    int sI = t + 256 * k;
    int row = sI >> 4, part = sI & 15;
    *(short8*)&tile[row][part * 8] =
        *(const short8*)(cat + (((size_t)(b * N_ + nbase + row)) << 8) + 128 + part * 8);
  }
  __syncthreads();
#pragma unroll
  for (int k = 0; k < 4; k++) {
    int sI = t + 256 * k;
    int dd = sI >> 3, part = sI & 7;
    unsigned short tmp[8];
#pragma unroll
    for (int j = 0; j < 8; j++) {
      int jj = part * 8 + j;
      tmp[j] = f2bf(bf2f(tile[jj][dd]) * rsv[jj]);
    }
    *(short8*)(vt + (((size_t)(b * 128 + dd)) << 11) + nbase + part * 8) = *(short8*)tmp;
  }
}

// ---------- k3: h' = P_un @ V'; out = c*x + (1-c)*relu(h') ----------
// grid (N/32, B); 4 waves; wave w owns d-group [w*32, w*32+32); j-tile 128.
__global__ __launch_bounds__(256) void k3(const unsigned short* __restrict__ pun,
                                          const unsigned short* __restrict__ vt,
                                          const float* __restrict__ x,
                                          const float* __restrict__ gw,
                                          const float* __restrict__ gb,
                                          float* __restrict__ out) {
  __shared__ char smem[40960];
  // [0,8192): A-tile P_un 32 x 128j   [8192,40960): B-tile vt 128d x 128j
  const int t = threadIdx.x, w = t >> 6, lane = t & 63;
  const int q = lane >> 4, l15 = lane & 15;
  const int b = blockIdx.y, i0 = blockIdx.x * 32;
  const size_t bN = (size_t)b * N_;
  unsigned short* pa = (unsigned short*)smem;
  unsigned short* vb = (unsigned short*)(smem + 8192);

  f32x4 acc[2][2];
#pragma unroll
  for (int ih = 0; ih < 2; ih++)
#pragma unroll
    for (int dh = 0; dh < 2; dh++) acc[ih][dh] = (f32x4){0.f, 0.f, 0.f, 0.f};

  for (int jt = 0; jt < N_ / 128; jt++) {
    const int j0 = jt * 128;
#pragma unroll
    for (int it = 0; it < 10; it++) {
      int sI = it * 256 + t;
      const unsigned short* g;
      if (sI < 512) {
        int row = sI >> 4, c = sI & 15;
        g = pun + (((size_t)(bN + i0 + row)) << 11) + j0 + ((c ^ (row & 7)) * 8);
      } else {
        int s2 = sI - 512;
        int dd = s2 >> 4, c = s2 & 15;
        g = vt + (((size_t)(b * 128 + dd)) << 11) + j0 + ((c ^ (dd & 7)) * 8);
      }
      GLL(g, smem + sI * 16);
    }
    __syncthreads();
#pragma unroll
    for (int ks = 0; ks < 4; ks++) {
      short8 af[2], bf[2];
#pragma unroll
      for (int ih = 0; ih < 2; ih++) {
        int m = ih * 16 + l15;
        af[ih] = *(short8*)(pa + m * 128 + (((ks * 4 + q) ^ (m & 7)) * 8));
      }
#pragma unroll
      for (int dh = 0; dh < 2; dh++) {
        int d = w * 32 + dh * 16 + l15;
        bf[dh] = *(short8*)(vb + d * 128 + (((ks * 4 + q) ^ (d & 7)) * 8));
      }
      acc[0][0] = __builtin_amdgcn_mfma_f32_16x16x32_bf16(af[0], bf[0], acc[0][0], 0, 0, 0);
      acc[0][1] = __builtin_amdgcn_mfma_f32_16x16x32_bf16(af[0], bf[1], acc[0][1], 0, 0, 0);
      acc[1][0] = __builtin_amdgcn_mfma_f32_16x16x32_bf16(af[1], bf[0], acc[1][0], 0, 0, 0);
      acc[1][1] = __builtin_amdgcn_mfma_f32_16x16x32_bf16(af[1], bf[1], acc[1][1], 0, 0, 0);
    }
    __syncthreads();
  }
  // epilogue: relu -> LDS f32, gate, sigmoid, blend, store
  float* hs = (float*)smem;            // 32 x 132 f32 = 16896 B
  float* co = (float*)(smem + 16896);  // 32 f32
#pragma unroll
  for (int ih = 0; ih < 2; ih++)
#pragma unroll
    for (int dh = 0; dh < 2; dh++)
#pragma unroll
      for (int r = 0; r < 4; r++) {
        int row = ih * 16 + q * 4 + r;
        int d = w * 32 + dh * 16 + l15;
        hs[row * 132 + d] = fmaxf(acc[ih][dh][r], 0.f);
      }
  __syncthreads();
  {
    int grow = t >> 3, sub = t & 7;
    const float* xr = x + (((size_t)(bN + i0 + grow)) << 7);
    float z = 0.f;
#pragma unroll
    for (int k = 0; k < 16; k++) {
      int dd = sub + 8 * k;
      z += gw[dd] * xr[dd] + gw[128 + dd] * hs[grow * 132 + dd];
    }
    z += __shfl_xor(z, 1, 64);
    z += __shfl_xor(z, 2, 64);
    z += __shfl_xor(z, 4, 64);
    if (sub == 0) co[grow] = 1.f / (1.f + __expf(-(z + gb[0])));
  }
  __syncthreads();
#pragma unroll
  for (int kk = 0; kk < 4; kk++) {
    int id = kk * 256 + t;
    int row = id >> 5, c4 = id & 31;
    size_t g = (((size_t)(bN + i0 + row)) << 7) + c4 * 4;
    f32x4 xv = *(const f32x4*)(x + g);
    f32x4 hv = *(const f32x4*)(hs + row * 132 + c4 * 4);
    float cf = co[row];
    f32x4 o;
#pragma unroll
    for (int e = 0; e < 4; e++) o[e] = cf * xv[e] + (1.f - cf) * hv[e];
    *(f32x4*)(out + g) = o;
  }
}

extern "C" void kernel_launch(void* const* d_in, const int* in_sizes, int n_in,
                              void* d_out, int out_size, void* d_ws, size_t ws_size,
                              hipStream_t stream) {
  const float* x   = (const float*)d_in[0];
  const float* adj = (const float*)d_in[1];
  const float* Ww  = (const float*)d_in[2];
  const float* Wb  = (const float*)d_in[3];
  const float* A   = (const float*)d_in[4];
  const float* gw  = (const float*)d_in[5];
  const float* gb  = (const float*)d_in[6];
  float* out = (float*)d_out;
  char* ws = (char*)d_ws;

  unsigned short* cat = (unsigned short*)(ws + CAT_OFF);
  unsigned short* vt  = (unsigned short*)(ws + VT_OFF);
  unsigned short* pun = (unsigned short*)(ws + PUN_OFF);
  float* s  = (float*)(ws + S_OFF);
  float* Wt = (float*)(ws + WT_OFF);

  hipMemsetAsync(s, 0, (size_t)B_ * N_ * sizeof(float), stream);
  k_wt<<<1, 256, 0, stream>>>(Ww, Wt);
  k1<<<(B_ * N_) / 8, 256, 0, stream>>>(x, Wt, Wb, A, cat);
  k2<<<dim3(N_ / 128, 16, B_), 256, 0, stream>>>(cat, adj, pun, s);
  k1v<<<dim3(N_ / 64, B_), 256, 0, stream>>>(cat, s, vt);
  k3<<<dim3(N_ / 32, B_), 256, 0, stream>>>(pun, vt, x, gw, gb, out);
}